// Round 1
// baseline (1040.382 us; speedup 1.0000x reference)
//
#include <hip/hip_runtime.h>
#include <hip/hip_bf16.h>
#include <math.h>

#define BN_EPS 1e-5f
#define TOPK_K 29

// ---------------------------------------------------------------------------
// Kernel 1: conv1(3->64, 3x3 SAME) + BN + ReLU + maxpool2  -> p1[64][64][16][16]
// grid (4, 64): blockIdx.x = ocg (16 oc each), blockIdx.y = image b. 256 thr.
// ---------------------------------------------------------------------------
__global__ __launch_bounds__(256) void conv1_kernel(
    const float* __restrict__ imgs, const float* __restrict__ w,
    const float* __restrict__ bconv, const float* __restrict__ scale,
    const float* __restrict__ bias, const float* __restrict__ mean,
    const float* __restrict__ var, float* __restrict__ p1)
{
    __shared__ float img_s[3][34][36];   // zero-padded 32x32, +1 border
    const int tid = (int)threadIdx.x;
    const int b = (int)blockIdx.y, ocg = (int)blockIdx.x;

    for (int i = tid; i < 3 * 34 * 36; i += 256) ((float*)img_s)[i] = 0.0f;
    __syncthreads();
    const float* ib = imgs + (size_t)b * 3 * 32 * 32;
    for (int i = tid; i < 3 * 32 * 32; i += 256) {
        int c = i >> 10, r = (i >> 5) & 31, x = i & 31;
        img_s[c][r + 1][x + 1] = ib[i];
    }
    __syncthreads();

    const int y = tid >> 4, x = tid & 15;   // pooled output coords (16x16)
    // conv rows needed: 2y-1..2y+2 -> padded rows 2y..2y+3; cols likewise.
    float win[3][4][4];
#pragma unroll
    for (int c = 0; c < 3; ++c)
#pragma unroll
        for (int r = 0; r < 4; ++r)
#pragma unroll
            for (int cc = 0; cc < 4; ++cc)
                win[c][r][cc] = img_s[c][2 * y + r][2 * x + cc];

    for (int k = 0; k < 16; ++k) {
        const int oc = ocg * 16 + k;
        const float* wp = w + oc * 27;
        float p00 = 0.f, p01 = 0.f, p10 = 0.f, p11 = 0.f;
#pragma unroll
        for (int c = 0; c < 3; ++c)
#pragma unroll
            for (int ky = 0; ky < 3; ++ky)
#pragma unroll
                for (int kx = 0; kx < 3; ++kx) {
                    float wv = wp[(c * 3 + ky) * 3 + kx];
                    p00 += win[c][ky][kx] * wv;
                    p01 += win[c][ky][kx + 1] * wv;
                    p10 += win[c][ky + 1][kx] * wv;
                    p11 += win[c][ky + 1][kx + 1] * wv;
                }
        const float a = scale[oc] / sqrtf(var[oc] + BN_EPS);
        const float c0 = (bconv[oc] - mean[oc]) * a + bias[oc];
        float m = fmaxf(fmaxf(p00 * a + c0, p01 * a + c0),
                        fmaxf(p10 * a + c0, p11 * a + c0));
        m = fmaxf(m, 0.0f);
        p1[(((size_t)b * 64 + oc) * 16 + y) * 16 + x] = m;
    }
}

// ---------------------------------------------------------------------------
// Kernel 2: conv2(64->128, 3x3 SAME) + BN + ReLU + maxpool2 -> feats[64][8192]
// grid (8, 64): blockIdx.x = ocg (16 oc), blockIdx.y = image b. 256 thr.
// LDS image [64][16][18]: col-padded (idx 0 and 17 are zeros), rows branch-masked.
// 72 KB -> 2 blocks/CU.
// ---------------------------------------------------------------------------
__global__ __launch_bounds__(256) void conv2_kernel(
    const float* __restrict__ p1, const float* __restrict__ w,
    const float* __restrict__ bconv, const float* __restrict__ scale,
    const float* __restrict__ bias, const float* __restrict__ mean,
    const float* __restrict__ var, float* __restrict__ feats)
{
    __shared__ float in_s[64][16][18];
    const int tid = (int)threadIdx.x;
    const int b = (int)blockIdx.y, ocg = (int)blockIdx.x;

    for (int i = tid; i < 64 * 16 * 18; i += 256) ((float*)in_s)[i] = 0.0f;
    __syncthreads();
    const float* pb = p1 + (size_t)b * 64 * 256;
    for (int i = tid; i < 64 * 256; i += 256) {
        int c = i >> 8, r = (i >> 4) & 15, x = i & 15;
        in_s[c][r][x + 1] = pb[i];
    }
    __syncthreads();

    const int pix = tid & 63;
    const int wv_id = __builtin_amdgcn_readfirstlane(tid >> 6);  // uniform wave id
    const int y = pix >> 3, x = pix & 7;   // pooled 8x8

    float acc[4][4];
#pragma unroll
    for (int k = 0; k < 4; ++k)
#pragma unroll
        for (int p = 0; p < 4; ++p) acc[k][p] = 0.0f;

    for (int c = 0; c < 64; ++c) {
        float win[4][4];
#pragma unroll
        for (int r = 0; r < 4; ++r) {
            int row = 2 * y - 1 + r;
            bool ok = (row >= 0) && (row < 16);
            const float2* rp = (const float2*)&in_s[c][ok ? row : 0][2 * x];
            float2 v0 = rp[0], v1 = rp[1];
            win[r][0] = ok ? v0.x : 0.0f;
            win[r][1] = ok ? v0.y : 0.0f;
            win[r][2] = ok ? v1.x : 0.0f;
            win[r][3] = ok ? v1.y : 0.0f;
        }
#pragma unroll
        for (int k = 0; k < 4; ++k) {
            const int oc = ocg * 16 + wv_id * 4 + k;   // wave-uniform
            const float* wp = w + ((size_t)oc * 64 + c) * 9;
#pragma unroll
            for (int ky = 0; ky < 3; ++ky)
#pragma unroll
                for (int kx = 0; kx < 3; ++kx) {
                    float wv = wp[ky * 3 + kx];
                    acc[k][0] += win[ky][kx] * wv;
                    acc[k][1] += win[ky][kx + 1] * wv;
                    acc[k][2] += win[ky + 1][kx] * wv;
                    acc[k][3] += win[ky + 1][kx + 1] * wv;
                }
        }
    }

#pragma unroll
    for (int k = 0; k < 4; ++k) {
        const int oc = ocg * 16 + wv_id * 4 + k;
        const float a = scale[oc] / sqrtf(var[oc] + BN_EPS);
        const float c0 = (bconv[oc] - mean[oc]) * a + bias[oc];
        float m = fmaxf(fmaxf(acc[k][0] * a + c0, acc[k][1] * a + c0),
                        fmaxf(acc[k][2] * a + c0, acc[k][3] * a + c0));
        m = fmaxf(m, 0.0f);
        feats[(size_t)b * 8192 + oc * 64 + pix] = m;
    }
}

// ---------------------------------------------------------------------------
// Kernel 3: L1 distance partials. lane=n (64 train rows/wave, t in registers),
// inner loop over 32 test rows with wave-uniform feats reads (-> s_load).
// grid (79, 32): x covers 128 n per block (2 n-groups x 2 b-halves = 4 waves),
// y = d-segment of 256. atomicAdd into D[b][n] (coalesced across lanes).
// ---------------------------------------------------------------------------
__global__ __launch_bounds__(256) void dist_kernel(
    const float* __restrict__ feats, const float* __restrict__ train,
    float* __restrict__ Dm)
{
    const int tid = (int)threadIdx.x;
    const int lane = tid & 63;
    const int wv = tid >> 6;
    const int bh = __builtin_amdgcn_readfirstlane(wv & 1);   // b half: 0 or 1
    const int ng = __builtin_amdgcn_readfirstlane(wv >> 1);  // n group: 0 or 1
    const int nbase = (int)blockIdx.x * 128 + ng * 64;
    const int seg = (int)blockIdx.y;                          // 256 d's each
    const int n = nbase + lane;
    const int nc = (n < 10000) ? n : 9999;

    const float* trow = train + (size_t)nc * 8192 + seg * 256;
    const float* fbase = feats + (size_t)(bh * 32) * 8192 + seg * 256;

    float acc[32];
#pragma unroll
    for (int i = 0; i < 32; ++i) acc[i] = 0.0f;

    for (int chunk = 0; chunk < 8; ++chunk) {
        float4 t[8];
#pragma unroll
        for (int q = 0; q < 8; ++q)
            t[q] = *(const float4*)(trow + chunk * 32 + q * 4);
#pragma unroll
        for (int bb = 0; bb < 32; ++bb) {
            const float4* fp = (const float4*)(fbase + (size_t)bb * 8192 + chunk * 32);
            float s0 = 0.0f, s1 = 0.0f;
#pragma unroll
            for (int q = 0; q < 8; ++q) {
                float4 f = fp[q];            // uniform address -> scalar load
                s0 += fabsf(t[q].x - f.x);
                s1 += fabsf(t[q].y - f.y);
                s0 += fabsf(t[q].z - f.z);
                s1 += fabsf(t[q].w - f.w);
            }
            acc[bb] += s0 + s1;
        }
    }

    if (n < 10000) {
#pragma unroll
        for (int bb = 0; bb < 32; ++bb)
            atomicAdd(&Dm[(size_t)(bh * 32 + bb) * 10000 + n], acc[bb]);
    }
}

// ---------------------------------------------------------------------------
// Kernel 4: per-row top-29 (exact, iterative min-extraction with cached
// per-thread minima + wave shfl reduce), then median/mode/exp-weight vote.
// grid 64 (one block per test row), 256 thr.
// ---------------------------------------------------------------------------
__global__ __launch_bounds__(256) void topk_kernel(
    const float* __restrict__ Dm, const int* __restrict__ labels,
    float* __restrict__ out)
{
    __shared__ float dv[10000];
    __shared__ float wv_s[4];
    __shared__ int wi_s[4];
    __shared__ int win_s;
    __shared__ float kv[TOPK_K];
    __shared__ int kidx[TOPK_K];

    const int b = (int)blockIdx.x, tid = (int)threadIdx.x;
    const int lane = tid & 63, wid = tid >> 6;
    const float* row = Dm + (size_t)b * 10000;

    for (int nn = tid; nn < 10000; nn += 256) dv[nn] = row[nn];
    __syncthreads();

    // initial per-thread minimum over strided subset
    float m = INFINITY;
    int mi = 0x7fffffff;
    for (int nn = tid; nn < 10000; nn += 256) {
        float v = dv[nn];
        if (v < m) { m = v; mi = nn; }   // first hit = lowest index on ties
    }

    for (int k = 0; k < TOPK_K; ++k) {
        float rv = m;
        int ri = mi;
#pragma unroll
        for (int s = 1; s < 64; s <<= 1) {
            float ov = __shfl_xor(rv, s, 64);
            int oi = __shfl_xor(ri, s, 64);
            if (ov < rv || (ov == rv && oi < ri)) { rv = ov; ri = oi; }
        }
        if (lane == 0) { wv_s[wid] = rv; wi_s[wid] = ri; }
        __syncthreads();
        if (tid == 0) {
            float bv = wv_s[0];
            int bi = wi_s[0];
            for (int q = 1; q < 4; ++q)
                if (wv_s[q] < bv || (wv_s[q] == bv && wi_s[q] < bi)) {
                    bv = wv_s[q]; bi = wi_s[q];
                }
            kv[k] = bv; kidx[k] = bi; win_s = bi;
            dv[bi] = INFINITY;
        }
        __syncthreads();
        const int wn = win_s;
        if ((wn & 255) == tid) {        // owner of extracted element rescans
            m = INFINITY; mi = 0x7fffffff;
            for (int nn = tid; nn < 10000; nn += 256) {
                float v = dv[nn];
                if (v < m) { m = v; mi = nn; }
            }
        }
    }

    if (tid == 0) {
        const float s = kv[14];          // median of 29 ascending values
        int cnt[10];
        int lab[TOPK_K];
        for (int c = 0; c < 10; ++c) cnt[c] = 0;
        for (int k = 0; k < TOPK_K; ++k) {
            lab[k] = labels[kidx[k]];
            cnt[lab[k]]++;
        }
        int pred = 0, bestc = cnt[0];
        for (int c = 1; c < 10; ++c)
            if (cnt[c] > bestc) { bestc = cnt[c]; pred = c; }
        float nr = 0.0f, dr = 0.0f;
        for (int k = 0; k < TOPK_K; ++k) {
            float wgt = expf(-kv[k] / s);
            dr += wgt;
            if (lab[k] == pred) nr += wgt;
        }
        const float frac = nr / dr;
        out[b * 2 + 0] = frac;
        out[b * 2 + 1] = 1.0f - frac;
    }
}

// ---------------------------------------------------------------------------
extern "C" void kernel_launch(void* const* d_in, const int* in_sizes, int n_in,
                              void* d_out, int out_size, void* d_ws, size_t ws_size,
                              hipStream_t stream) {
    const float* imgs = (const float*)d_in[0];
    const float* c1w = (const float*)d_in[1];
    const float* c1b = (const float*)d_in[2];
    const float* bn1s = (const float*)d_in[3];
    const float* bn1b = (const float*)d_in[4];
    const float* bn1m = (const float*)d_in[5];
    const float* bn1v = (const float*)d_in[6];
    const float* c2w = (const float*)d_in[7];
    const float* c2b = (const float*)d_in[8];
    const float* bn2s = (const float*)d_in[9];
    const float* bn2b = (const float*)d_in[10];
    const float* bn2m = (const float*)d_in[11];
    const float* bn2v = (const float*)d_in[12];
    const float* train = (const float*)d_in[13];
    const int* labels = (const int*)d_in[14];
    float* out = (float*)d_out;

    char* ws = (char*)d_ws;
    float* p1 = (float*)(ws);                        // 64*64*16*16*4 = 4,194,304 B
    float* feats = (float*)(ws + 4194304);           // 64*8192*4    = 2,097,152 B
    float* Dm = (float*)(ws + 4194304 + 2097152);    // 64*10000*4   = 2,560,000 B

    hipMemsetAsync(Dm, 0, (size_t)64 * 10000 * sizeof(float), stream);
    conv1_kernel<<<dim3(4, 64), 256, 0, stream>>>(imgs, c1w, c1b, bn1s, bn1b, bn1m, bn1v, p1);
    conv2_kernel<<<dim3(8, 64), 256, 0, stream>>>(p1, c2w, c2b, bn2s, bn2b, bn2m, bn2v, feats);
    dist_kernel<<<dim3(79, 32), 256, 0, stream>>>(feats, train, Dm);
    topk_kernel<<<64, 256, 0, stream>>>(Dm, labels, out);
}